// Round 18
// baseline (126.801 us; speedup 1.0000x reference)
//
#include <hip/hip_runtime.h>
#include <hip/hip_bf16.h>

// BLAST factorized linear, 4 kernels:
//   prep_vtf/prep_utf: frag-order weights via LDS transpose (coalesced R+W)
//   K1 : T[j][n][r] = sum_s X[n,j*256+s]*Vt[j,s,r]  (GEMM; T stored via LDS
//        transpose -> 1KB contiguous store instructions)
//   K2 : one wg per 16-row strip; T strip staged in LDS ONCE (64KB); loop all
//        16 o's: fold (LDS T + L2-broadcast S) -> u dbuf -> 16x256 GEMM
//        (frag-order utf) -> f32x4 stores. Kills the 16x o-grid T re-read.

typedef __bf16 bf16x8 __attribute__((ext_vector_type(8)));
typedef __bf16 bf16x4 __attribute__((ext_vector_type(4)));
typedef float  f32x4  __attribute__((ext_vector_type(4)));

#define IN_DIM  4096
#define OUT_DIM 4096
#define NROWS   8192
#define BJ      16
#define BO      16
#define RANK    128

__device__ __forceinline__ bf16x4 cvt4(f32x4 v) {
  bf16x4 r;
  r[0] = (__bf16)v[0]; r[1] = (__bf16)v[1]; r[2] = (__bf16)v[2]; r[3] = (__bf16)v[3];
  return r;
}
__device__ __forceinline__ f32x4 lo4(bf16x8 v) {
  return (f32x4){(float)v[0], (float)v[1], (float)v[2], (float)v[3]};
}
__device__ __forceinline__ f32x4 hi4(bf16x8 v) {
  return (f32x4){(float)v[4], (float)v[5], (float)v[6], (float)v[7]};
}

// ---- prep A: vtf via LDS transpose. One block per (j, ks): 128 blocks. ----
// vtf[(((j*8+rf)*8+ks)*64 + lh*16+l)*8 + e] = Vt[j][ks*32 + lh*8+e][rf*16 + l]
__global__ __launch_bounds__(256) void prep_vtf(
    const float* __restrict__ Vt, __bf16* __restrict__ vtf)
{
  __shared__ float t[32 * 129];
  const int tid = threadIdx.x;
  const int j   = blockIdx.x >> 3;
  const int ks  = blockIdx.x & 7;

  #pragma unroll
  for (int it = 0; it < 4; ++it) {
    const int c  = tid + it * 256;
    const int sr = c >> 5, r4 = c & 31;
    const f32x4 v = *(const f32x4*)(Vt + ((size_t)(j * 256 + ks * 32 + sr)) * RANK + r4 * 4);
    t[sr * 129 + r4 * 4 + 0] = v[0];
    t[sr * 129 + r4 * 4 + 1] = v[1];
    t[sr * 129 + r4 * 4 + 2] = v[2];
    t[sr * 129 + r4 * 4 + 3] = v[3];
  }
  __syncthreads();

  const int lane = tid & 63;
  const int l = lane & 15, lh = lane >> 4;
  #pragma unroll
  for (int h = 0; h < 2; ++h) {
    const int rf = (tid >> 6) + h * 4;
    bf16x8 o8;
    #pragma unroll
    for (int e = 0; e < 8; ++e)
      o8[e] = (__bf16)t[(lh * 8 + e) * 129 + rf * 16 + l];
    *(bf16x8*)&vtf[(((size_t)(j * 8 + rf) * 8 + ks) * 64 + lane) * 8] = o8;
  }
}

// ---- prep B: utf via LDS transpose. One block per (o, ks): 64 blocks. ----
// utf[(((o*16+pf)*4+ks)*64 + lh*16+l)*8 + e] = U[o][ks*32 + lh*8+e][pf*16 + l]
__global__ __launch_bounds__(256) void prep_utf(
    const float* __restrict__ U, __bf16* __restrict__ utf)
{
  __shared__ float t[32 * 257];
  const int tid = threadIdx.x;
  const int o   = blockIdx.x >> 2;
  const int ks  = blockIdx.x & 3;

  #pragma unroll
  for (int it = 0; it < 8; ++it) {
    const int c  = tid + it * 256;
    const int rr = c >> 6, p4 = c & 63;
    const f32x4 v = *(const f32x4*)(U + ((size_t)(o * RANK + ks * 32 + rr)) * 256 + p4 * 4);
    t[rr * 257 + p4 * 4 + 0] = v[0];
    t[rr * 257 + p4 * 4 + 1] = v[1];
    t[rr * 257 + p4 * 4 + 2] = v[2];
    t[rr * 257 + p4 * 4 + 3] = v[3];
  }
  __syncthreads();

  const int lane = tid & 63;
  const int l = lane & 15, lh = lane >> 4;
  #pragma unroll
  for (int h = 0; h < 4; ++h) {
    const int pf = (tid >> 6) + h * 4;
    bf16x8 o8;
    #pragma unroll
    for (int e = 0; e < 8; ++e)
      o8[e] = (__bf16)t[(lh * 8 + e) * 257 + pf * 16 + l];
    *(bf16x8*)&utf[(((size_t)(o * 16 + pf) * 4 + ks) * 64 + lane) * 8] = o8;
  }
}

// ---- K1: T-tile GEMM. wg=256 (4 waves), tile 64 rows x 128 r, one j. ----
// T stored j-major T[j][n][128] via LDS transpose (1KB contiguous stores).
__global__ __launch_bounds__(256, 4) void k1_T(
    const float* __restrict__ x, const __bf16* __restrict__ vtf,
    __bf16* __restrict__ T)
{
  __shared__ __bf16 X_lds[64 * 256];   // 32 KB; reused as T_st[64][128] after MFMA

  const int tid  = threadIdx.x;
  const int lane = tid & 63;
  const int w    = tid >> 6;
  const int l15  = lane & 15;
  const int lhi  = lane >> 4;
  const int b    = blockIdx.x;
  const int j    = (b >> 3) & 15;
  const int mt   = (b & 7) * 16 + (b >> 7);
  const size_t rowbase = (size_t)mt * 64;

  #pragma unroll
  for (int i = 0; i < 16; ++i) {
    const int row = w * 16 + i;
    const f32x4 v = __builtin_nontemporal_load(
        (const f32x4*)(x + (rowbase + row) * IN_DIM + j * 256 + lane * 4));
    const int c = (lane >> 1) ^ (row & 15);
    *(bf16x4*)&X_lds[row * 256 + c * 8 + (lane & 1) * 4] = cvt4(v);
  }
  __syncthreads();

  f32x4 acc[2][4];
  #pragma unroll
  for (int a = 0; a < 2; ++a)
    #pragma unroll
    for (int c = 0; c < 4; ++c) acc[a][c] = (f32x4){0.f, 0.f, 0.f, 0.f};

  const __bf16* va = vtf + ((size_t)(j * 8 + w * 2) * 8) * 512 + lane * 8;
  #pragma unroll
  for (int ks = 0; ks < 8; ++ks) {
    bf16x8 bfr[4];
    #pragma unroll
    for (int nf = 0; nf < 4; ++nf) {
      const int c = (ks * 4 + lhi) ^ l15;
      bfr[nf] = *(const bf16x8*)&X_lds[(nf * 16 + l15) * 256 + c * 8];
    }
    const bf16x8 a0 = *(const bf16x8*)(va + (size_t)ks * 512);
    const bf16x8 a1 = *(const bf16x8*)(va + (size_t)(8 + ks) * 512);
    #pragma unroll
    for (int nf = 0; nf < 4; ++nf) {
      acc[0][nf] = __builtin_amdgcn_mfma_f32_16x16x32_bf16(a0, bfr[nf], acc[0][nf], 0, 0, 0);
      acc[1][nf] = __builtin_amdgcn_mfma_f32_16x16x32_bf16(a1, bfr[nf], acc[1][nf], 0, 0, 0);
    }
  }
  __syncthreads();   // X_lds reads done; reuse as T staging

  // stage D=[r,n] fragments into T_st[64][128] (swizzled 8B chunks)
  #pragma unroll
  for (int rfi = 0; rfi < 2; ++rfi)
    #pragma unroll
    for (int nf = 0; nf < 4; ++nf) {
      const int n  = nf * 16 + l15;
      const int c8 = (w * 2 + rfi) * 4 + lhi;        // 8B chunk in [0,32)
      const int cs = c8 ^ ((n & 7) << 2);
      *(bf16x4*)&X_lds[n * 128 + cs * 4] = cvt4(acc[rfi][nf]);
    }
  __syncthreads();

  // store: wave w -> rows w*16..+16; each instr = 4 rows x 256B = 1KB contiguous
  #pragma unroll
  for (int i = 0; i < 4; ++i) {
    const int row = w * 16 + i * 4 + (lane >> 4);
    const int m   = lane & 15;                       // 16B chunk
    const int ms  = m ^ ((row & 7) << 1);
    const bf16x8 v = *(const bf16x8*)&X_lds[row * 128 + ms * 8];
    *(bf16x8*)&T[((size_t)j * NROWS + rowbase + row) * RANK + m * 8] = v;
  }
}

// ---- K2: one wg per 16-row strip (512 thr, 8 waves); T in LDS; all 16 o's. ----
__global__ __launch_bounds__(512, 2) void k2_fused(
    const __bf16* __restrict__ T, const float* __restrict__ S,
    const __bf16* __restrict__ utf, const float* __restrict__ bias,
    float* __restrict__ out)
{
  __shared__ __bf16 T_lds[BJ * 16 * RANK];   // 64 KB  [j][n][r]
  __shared__ __bf16 u_lds[2][16 * RANK];     // 8 KB, 16B chunk c -> c ^ n

  const int tid  = threadIdx.x;
  const int lane = tid & 63;
  const int w    = tid >> 6;            // 0..7
  const int l15  = lane & 15;
  const int lhi  = lane >> 4;
  const size_t rowbase = (size_t)blockIdx.x * 16;

  // ---- stage T strip: 64KB, 8 iters, 1KB contiguous per wave-instr ----
  #pragma unroll
  for (int it = 0; it < 8; ++it) {
    const int idx = it * 512 + tid;          // 16B chunk id in [0,4096)
    const int j = idx >> 8, q = idx & 255;
    const int n = q >> 4, m = q & 15;
    const bf16x8 v = *(const bf16x8*)&T[((size_t)j * NROWS + rowbase + n) * RANK + m * 8];
    *(bf16x8*)&T_lds[(j * 16 + n) * RANK + m * 8] = v;
  }
  __syncthreads();

  const int fn = tid >> 5;       // fold row 0..15
  const int rs = tid & 31;       // r = rs*4 .. +4

  for (int o = 0; o < BO; ++o) {
    // ---- fold: u[fn][rs*4..+4] = sum_j S[o,j,r]*T[j][fn][r] ----
    {
      f32x4 acc = {0.f, 0.f, 0.f, 0.f};
      const float* sp = S + (size_t)o * (BJ * RANK) + rs * 4;
      #pragma unroll
      for (int j = 0; j < BJ; ++j) {
        const bf16x4 tv = *(const bf16x4*)&T_lds[(j * 16 + fn) * RANK + rs * 4];
        const f32x4 sv = *(const f32x4*)(sp + j * RANK);
        const f32x4 tf = {(float)tv[0], (float)tv[1], (float)tv[2], (float)tv[3]};
        acc = sv * tf + acc;
      }
      const int c16 = rs >> 1, h = rs & 1;
      const int cs  = c16 ^ fn;
      *(bf16x4*)&u_lds[o & 1][fn * RANK + cs * 8 + h * 4] = cvt4(acc);
    }
    __syncthreads();

    // ---- GEMM: wave w -> pf = 2w, 2w+1 (cols 32); D=[p,n] -> f32x4 stores ----
    {
      bf16x8 ubf[4];
      #pragma unroll
      for (int ks = 0; ks < 4; ++ks) {
        const int cs = (ks * 4 + lhi) ^ l15;
        ubf[ks] = *(const bf16x8*)&u_lds[o & 1][l15 * RANK + cs * 8];
      }
      #pragma unroll
      for (int q = 0; q < 2; ++q) {
        const int pf = w * 2 + q;
        f32x4 acc = {0.f, 0.f, 0.f, 0.f};
        const __bf16* uab = utf + ((size_t)((o * 16 + pf) * 4)) * 512 + lane * 8;
        #pragma unroll
        for (int ks = 0; ks < 4; ++ks) {
          const bf16x8 af = *(const bf16x8*)(uab + (size_t)ks * 512);
          acc = __builtin_amdgcn_mfma_f32_16x16x32_bf16(af, ubf[ks], acc, 0, 0, 0);
        }
        const int colb = o * 256 + pf * 16 + lhi * 4;
        const f32x4 bv = *(const f32x4*)(bias + colb);
        *(f32x4*)(out + (rowbase + l15) * OUT_DIM + colb) = acc + bv;
      }
    }
    // dbuf: fold(o+1) writes the other buffer; buffer o&1 is next written at
    // fold(o+2), which is after barrier(o+1) -> GEMM(o) reads are safe.
  }
}

extern "C" void kernel_launch(void* const* d_in, const int* in_sizes, int n_in,
                              void* d_out, int out_size, void* d_ws, size_t ws_size,
                              hipStream_t stream) {
  const float* x    = (const float*)d_in[0];
  const float* S    = (const float*)d_in[1];
  const float* U    = (const float*)d_in[2];
  const float* Vt   = (const float*)d_in[3];
  const float* bias = (const float*)d_in[4];
  float* out = (float*)d_out;

  __bf16* vtf = (__bf16*)d_ws;                       // 1 MB
  __bf16* utf = vtf + (size_t)BJ * 8 * 8 * 512;      // 1 MB
  __bf16* T   = utf + (size_t)BO * 16 * 4 * 512;     // 32 MB: T[16][8192][128]

  prep_vtf<<<BJ * 8, 256, 0, stream>>>(Vt, vtf);
  prep_utf<<<BO * 4, 256, 0, stream>>>(U, utf);
  k1_T<<<(NROWS / 64) * BJ, 256, 0, stream>>>(x, vtf, T);
  k2_fused<<<NROWS / 16, 512, 0, stream>>>(T, S, utf, bias, out);
}

// Round 19
// 100.897 us; speedup vs baseline: 1.2567x; 1.2567x over previous
//
#include <hip/hip_runtime.h>
#include <hip/hip_bf16.h>

// BLAST factorized linear, 4 kernels (best-of composition):
//   prep_vtf/prep_utf: frag-order weights via LDS transpose (coalesced R+W)
//   K1 : T[j][n][r] = sum_s X[n,j*256+s]*Vt[j,s,r]  (GEMM; T stored via LDS
//        transpose -> 1KB contiguous stores)  [R18, ~27us]
//   K2 : o-grid fused fold+GEMM (R14 structure, ~60us): per (64-row, o):
//        S->LDS, fold in regs (4-row amortized S reads, full-sector T loads),
//        u XOR-swizzled LDS, 1 barrier, MFMA GEMM (frag-order utf), nt stores.

typedef __bf16 bf16x8 __attribute__((ext_vector_type(8)));
typedef __bf16 bf16x4 __attribute__((ext_vector_type(4)));
typedef float  f32x4  __attribute__((ext_vector_type(4)));

#define IN_DIM  4096
#define OUT_DIM 4096
#define NROWS   8192
#define BJ      16
#define BO      16
#define RANK    128

__device__ __forceinline__ bf16x4 cvt4(f32x4 v) {
  bf16x4 r;
  r[0] = (__bf16)v[0]; r[1] = (__bf16)v[1]; r[2] = (__bf16)v[2]; r[3] = (__bf16)v[3];
  return r;
}
__device__ __forceinline__ f32x4 lo4(bf16x8 v) {
  return (f32x4){(float)v[0], (float)v[1], (float)v[2], (float)v[3]};
}
__device__ __forceinline__ f32x4 hi4(bf16x8 v) {
  return (f32x4){(float)v[4], (float)v[5], (float)v[6], (float)v[7]};
}

// ---- prep A: vtf via LDS transpose. One block per (j, ks): 128 blocks. ----
__global__ __launch_bounds__(256) void prep_vtf(
    const float* __restrict__ Vt, __bf16* __restrict__ vtf)
{
  __shared__ float t[32 * 129];
  const int tid = threadIdx.x;
  const int j   = blockIdx.x >> 3;
  const int ks  = blockIdx.x & 7;

  #pragma unroll
  for (int it = 0; it < 4; ++it) {
    const int c  = tid + it * 256;
    const int sr = c >> 5, r4 = c & 31;
    const f32x4 v = *(const f32x4*)(Vt + ((size_t)(j * 256 + ks * 32 + sr)) * RANK + r4 * 4);
    t[sr * 129 + r4 * 4 + 0] = v[0];
    t[sr * 129 + r4 * 4 + 1] = v[1];
    t[sr * 129 + r4 * 4 + 2] = v[2];
    t[sr * 129 + r4 * 4 + 3] = v[3];
  }
  __syncthreads();

  const int lane = tid & 63;
  const int l = lane & 15, lh = lane >> 4;
  #pragma unroll
  for (int h = 0; h < 2; ++h) {
    const int rf = (tid >> 6) + h * 4;
    bf16x8 o8;
    #pragma unroll
    for (int e = 0; e < 8; ++e)
      o8[e] = (__bf16)t[(lh * 8 + e) * 129 + rf * 16 + l];
    *(bf16x8*)&vtf[(((size_t)(j * 8 + rf) * 8 + ks) * 64 + lane) * 8] = o8;
  }
}

// ---- prep B: utf via LDS transpose. One block per (o, ks): 64 blocks. ----
__global__ __launch_bounds__(256) void prep_utf(
    const float* __restrict__ U, __bf16* __restrict__ utf)
{
  __shared__ float t[32 * 257];
  const int tid = threadIdx.x;
  const int o   = blockIdx.x >> 2;
  const int ks  = blockIdx.x & 3;

  #pragma unroll
  for (int it = 0; it < 8; ++it) {
    const int c  = tid + it * 256;
    const int rr = c >> 6, p4 = c & 63;
    const f32x4 v = *(const f32x4*)(U + ((size_t)(o * RANK + ks * 32 + rr)) * 256 + p4 * 4);
    t[rr * 257 + p4 * 4 + 0] = v[0];
    t[rr * 257 + p4 * 4 + 1] = v[1];
    t[rr * 257 + p4 * 4 + 2] = v[2];
    t[rr * 257 + p4 * 4 + 3] = v[3];
  }
  __syncthreads();

  const int lane = tid & 63;
  const int l = lane & 15, lh = lane >> 4;
  #pragma unroll
  for (int h = 0; h < 4; ++h) {
    const int pf = (tid >> 6) + h * 4;
    bf16x8 o8;
    #pragma unroll
    for (int e = 0; e < 8; ++e)
      o8[e] = (__bf16)t[(lh * 8 + e) * 257 + pf * 16 + l];
    *(bf16x8*)&utf[(((size_t)(o * 16 + pf) * 4 + ks) * 64 + lane) * 8] = o8;
  }
}

// ---- K1: T-tile GEMM. wg=256 (4 waves), tile 64 rows x 128 r, one j. ----
// T stored j-major T[j][n][128] via LDS transpose (1KB contiguous stores).
__global__ __launch_bounds__(256, 4) void k1_T(
    const float* __restrict__ x, const __bf16* __restrict__ vtf,
    __bf16* __restrict__ T)
{
  __shared__ __bf16 X_lds[64 * 256];   // 32 KB; reused as T_st[64][128] after MFMA

  const int tid  = threadIdx.x;
  const int lane = tid & 63;
  const int w    = tid >> 6;
  const int l15  = lane & 15;
  const int lhi  = lane >> 4;
  const int b    = blockIdx.x;
  const int j    = (b >> 3) & 15;
  const int mt   = (b & 7) * 16 + (b >> 7);
  const size_t rowbase = (size_t)mt * 64;

  #pragma unroll
  for (int i = 0; i < 16; ++i) {
    const int row = w * 16 + i;
    const f32x4 v = __builtin_nontemporal_load(
        (const f32x4*)(x + (rowbase + row) * IN_DIM + j * 256 + lane * 4));
    const int c = (lane >> 1) ^ (row & 15);
    *(bf16x4*)&X_lds[row * 256 + c * 8 + (lane & 1) * 4] = cvt4(v);
  }
  __syncthreads();

  f32x4 acc[2][4];
  #pragma unroll
  for (int a = 0; a < 2; ++a)
    #pragma unroll
    for (int c = 0; c < 4; ++c) acc[a][c] = (f32x4){0.f, 0.f, 0.f, 0.f};

  const __bf16* va = vtf + ((size_t)(j * 8 + w * 2) * 8) * 512 + lane * 8;
  #pragma unroll
  for (int ks = 0; ks < 8; ++ks) {
    bf16x8 bfr[4];
    #pragma unroll
    for (int nf = 0; nf < 4; ++nf) {
      const int c = (ks * 4 + lhi) ^ l15;
      bfr[nf] = *(const bf16x8*)&X_lds[(nf * 16 + l15) * 256 + c * 8];
    }
    const bf16x8 a0 = *(const bf16x8*)(va + (size_t)ks * 512);
    const bf16x8 a1 = *(const bf16x8*)(va + (size_t)(8 + ks) * 512);
    #pragma unroll
    for (int nf = 0; nf < 4; ++nf) {
      acc[0][nf] = __builtin_amdgcn_mfma_f32_16x16x32_bf16(a0, bfr[nf], acc[0][nf], 0, 0, 0);
      acc[1][nf] = __builtin_amdgcn_mfma_f32_16x16x32_bf16(a1, bfr[nf], acc[1][nf], 0, 0, 0);
    }
  }
  __syncthreads();   // X_lds reads done; reuse as T staging

  #pragma unroll
  for (int rfi = 0; rfi < 2; ++rfi)
    #pragma unroll
    for (int nf = 0; nf < 4; ++nf) {
      const int n  = nf * 16 + l15;
      const int c8 = (w * 2 + rfi) * 4 + lhi;        // 8B chunk in [0,32)
      const int cs = c8 ^ ((n & 7) << 2);
      *(bf16x4*)&X_lds[n * 128 + cs * 4] = cvt4(acc[rfi][nf]);
    }
  __syncthreads();

  #pragma unroll
  for (int i = 0; i < 4; ++i) {
    const int row = w * 16 + i * 4 + (lane >> 4);
    const int m   = lane & 15;
    const int ms  = m ^ ((row & 7) << 1);
    const bf16x8 v = *(const bf16x8*)&X_lds[row * 128 + ms * 8];
    *(bf16x8*)&T[((size_t)j * NROWS + rowbase + row) * RANK + m * 8] = v;
  }
}

// ---- K2: o-grid fused fold + out-GEMM (R14). wg=256, 64 rows x one o. ----
// grid b: o = (b>>3)&15, mt = (b&7)*16 + (b>>7).
__global__ __launch_bounds__(256, 4) void k2_fused(
    const __bf16* __restrict__ T, const float* __restrict__ S,
    const __bf16* __restrict__ utf, const float* __restrict__ bias,
    float* __restrict__ out)
{
  __shared__ float  S_lds[BJ * RANK];    // 8 KB, linear [j][r]
  __shared__ __bf16 u_lds[64 * RANK];    // 16 KB, 16B chunk c -> c ^ (n&15)

  const int tid = threadIdx.x;
  const int b   = blockIdx.x;
  const int o   = (b >> 3) & 15;
  const int mt  = (b & 7) * 16 + (b >> 7);
  const size_t rowbase = (size_t)mt * 64;

  {
    const float* sb = S + (size_t)o * (BJ * RANK);
    #pragma unroll
    for (int h = 0; h < 2; ++h) {
      const int idx = tid + h * 256;
      *(f32x4*)&S_lds[idx * 4] = *(const f32x4*)(sb + idx * 4);
    }
  }
  __syncthreads();

  {
    const int nb = tid >> 4;          // rows nb*4..+4
    const int rs = tid & 15;          // r = rs*8..+8
    const __bf16* tg = T + (rowbase + nb * 4) * RANK + rs * 8;
    const size_t jstride = (size_t)NROWS * RANK;
    f32x4 uac[4][2];
    #pragma unroll
    for (int i = 0; i < 4; ++i) {
      uac[i][0] = (f32x4){0.f, 0.f, 0.f, 0.f};
      uac[i][1] = (f32x4){0.f, 0.f, 0.f, 0.f};
    }

    #pragma unroll 4
    for (int jb = 0; jb < BJ; ++jb) {
      const __bf16* tj = tg + (size_t)jb * jstride;
      bf16x8 tv[4];
      #pragma unroll
      for (int i = 0; i < 4; ++i) tv[i] = *(const bf16x8*)(tj + i * RANK);
      const float* sj = &S_lds[jb * RANK + rs * 8];
      const f32x4 s0 = *(const f32x4*)(sj);
      const f32x4 s1 = *(const f32x4*)(sj + 4);
      #pragma unroll
      for (int i = 0; i < 4; ++i) {
        uac[i][0] = s0 * lo4(tv[i]) + uac[i][0];
        uac[i][1] = s1 * hi4(tv[i]) + uac[i][1];
      }
    }
    #pragma unroll
    for (int i = 0; i < 4; ++i) {
      const int n = nb * 4 + i;
      bf16x8 uw;
      const f32x4 a = uac[i][0], bb = uac[i][1];
      uw[0]=(__bf16)a[0];  uw[1]=(__bf16)a[1];  uw[2]=(__bf16)a[2];  uw[3]=(__bf16)a[3];
      uw[4]=(__bf16)bb[0]; uw[5]=(__bf16)bb[1]; uw[6]=(__bf16)bb[2]; uw[7]=(__bf16)bb[3];
      const int swz = rs ^ (n & 15);
      *(bf16x8*)&u_lds[n * RANK + swz * 8] = uw;
    }
  }
  __syncthreads();

  {
    const int lane = tid & 63;
    const int w    = tid >> 6;
    const int l15  = lane & 15;
    const int lhi  = lane >> 4;

    f32x4 acc[4][4];
    #pragma unroll
    for (int a = 0; a < 4; ++a)
      #pragma unroll
      for (int c = 0; c < 4; ++c) acc[a][c] = (f32x4){0.f, 0.f, 0.f, 0.f};

    #pragma unroll
    for (int ks = 0; ks < 4; ++ks) {
      bf16x8 ubf[4];
      #pragma unroll
      for (int nf = 0; nf < 4; ++nf) {
        const int swz = (ks * 4 + lhi) ^ l15;
        ubf[nf] = *(const bf16x8*)&u_lds[(nf * 16 + l15) * RANK + swz * 8];
      }
      #pragma unroll
      for (int pi = 0; pi < 4; ++pi) {
        const bf16x8 af = *(const bf16x8*)(
            utf + ((size_t)((o * 16 + w * 4 + pi) * 4 + ks)) * 512 + lane * 8);
        #pragma unroll
        for (int nf = 0; nf < 4; ++nf)
          acc[pi][nf] = __builtin_amdgcn_mfma_f32_16x16x32_bf16(af, ubf[nf], acc[pi][nf], 0, 0, 0);
      }
    }

    #pragma unroll
    for (int pi = 0; pi < 4; ++pi) {
      const int colb = o * 256 + (w * 4 + pi) * 16 + lhi * 4;
      const f32x4 bv = *(const f32x4*)(bias + colb);
      #pragma unroll
      for (int nf = 0; nf < 4; ++nf) {
        __builtin_nontemporal_store(acc[pi][nf] + bv,
            (f32x4*)(out + (rowbase + nf * 16 + l15) * OUT_DIM + colb));
      }
    }
  }
}

extern "C" void kernel_launch(void* const* d_in, const int* in_sizes, int n_in,
                              void* d_out, int out_size, void* d_ws, size_t ws_size,
                              hipStream_t stream) {
  const float* x    = (const float*)d_in[0];
  const float* S    = (const float*)d_in[1];
  const float* U    = (const float*)d_in[2];
  const float* Vt   = (const float*)d_in[3];
  const float* bias = (const float*)d_in[4];
  float* out = (float*)d_out;

  __bf16* vtf = (__bf16*)d_ws;                       // 1 MB
  __bf16* utf = vtf + (size_t)BJ * 8 * 8 * 512;      // 1 MB
  __bf16* T   = utf + (size_t)BO * 16 * 4 * 512;     // 32 MB: T[16][8192][128]

  prep_vtf<<<BJ * 8, 256, 0, stream>>>(Vt, vtf);
  prep_utf<<<BO * 4, 256, 0, stream>>>(U, utf);
  k1_T<<<(NROWS / 64) * BJ, 256, 0, stream>>>(x, vtf, T);
  k2_fused<<<(NROWS / 64) * BO, 256, 0, stream>>>(T, S, utf, bias, out);
}